// Round 11
// baseline (222.410 us; speedup 1.0000x reference)
//
#include <hip/hip_runtime.h>
#include <cstdint>
#include <cstddef>

#define NP  1024
#define FD  10
#define BSZ 128
#define TPB 512   // 8 waves; each wave owns 128 rows (4 row-tiles of 32)
#define NW  8
#define RT  4     // row-tiles per wave

// R11 = R10 pass-1/epilogue verbatim, restructured as persistent 2-unit
// blocks. grid 512 (2 blocks/CU, one flat round); block bx processes
// bid = 2bx (d=0: rows=ag, cols=dg) then bid = 2bx+1 (d=1: rows=dg, cols=ag).
// While pass1(u0) runs, u1's raw inputs (24 floats/thread) are in flight in
// registers (T14 issue-early/write-late); the u0->u1 restage then has no
// exposed global latency. Halves block launches, staging ramps, atomics.
// Rationale: R4-R10 pinned at 106-110us with MFMA 27%, VALU 49-73%, LDS/HBM
// idle -- no pipe bound; the invariant was 1024 blocks x 4 occupancy rounds
// of serial per-block phase chains. This targets exactly that.
// Numerics IDENTICAL to R10 (absmax 0.0 x9): d = cs - 2 r.c via bf16 split-3
// in K=32, two chained 32x32x16 MFMAs (4 concurrent rt-chains); tile-level
// (min, ct) tracking, strict < first-ct; shfl_xor(32) lexicographic merge;
// 32-col fp32 global rescan epilogue (bit-identical staging-chain recompute,
// ascending j + strict < = reference first-index argmin).
typedef __attribute__((ext_vector_type(8)))  __bf16 bf16x8;
typedef __attribute__((ext_vector_type(16))) float  f32x16;

__device__ inline unsigned int pk2(__bf16 a, __bf16 b) {
    union { __bf16 h; unsigned short u; } ua, ub;
    ua.h = a; ub.h = b;
    return (unsigned int)ua.u | ((unsigned int)ub.u << 16);
}

__device__ inline void split3(float x, __bf16& h, __bf16& m, __bf16& l) {
    h = (__bf16)x;
    float r1 = x - (float)h;    // exact (h carries x's exponent, 8-bit mantissa)
    m = (__bf16)r1;
    float r2 = r1 - (float)m;   // exact
    l = (__bf16)r2;
}

__device__ inline float min3f(float a, float b, float c) {
    return fminf(fminf(a, b), c);   // fuses to v_min3_f32; order-invariant exact
}

extern "C" __global__ __launch_bounds__(TPB, 4)   // VGPR cap 128
void chamfer_pairs(const float* __restrict__ ag, const float* __restrict__ dg,
                   const float* __restrict__ nmean, const float* __restrict__ nstd,
                   float* __restrict__ out /* [BSZ], pre-zeroed */)
{
    // Four 8-byte half-planes {Ch, Cm, Cl, cs3} = 32 KB, + dedicated scratch
    // for per-row (ct, thr) so u1's restage can't clobber u0's epilogue.
    __shared__ __align__(16) unsigned int ldsH[4 * NP * 2];
    __shared__ int   sCtA[NP];
    __shared__ float sThrA[NP];
    __shared__ float red[NW];

    const int bx   = blockIdx.x;        // 0..511; pair = bx
    const int tid  = threadIdx.x;
    const int wv   = tid >> 6;          // wave 0..7
    const int l    = tid & 63;
    const int ln   = l & 31;            // lane's row slot / col slot
    const int hh   = l >> 5;            // k-half owner

    const float* srcA = ag + (size_t)bx * (NP * FD);   // achieved (u0 rows, u1 cols)
    const float* srcD = dg + (size_t)bx * (NP * FD);   // desired  (u0 cols, u1 rows)

    // -2*(std, mean) for vis features 5..8 (uniform -> scalar regs).
    const float s5 = -2.0f * nstd[5], m5 = -2.0f * nmean[5];
    const float s6 = -2.0f * nstd[6], m6 = -2.0f * nmean[6];
    const float s7 = -2.0f * nstd[7], m7 = -2.0f * nmean[7];
    const float s8 = -2.0f * nstd[8], m8 = -2.0f * nmean[8];
    const float std0 = nstd[0], mean0 = nmean[0];
    const float std1 = nstd[1], mean1 = nmean[1];

    bf16x8 B1[RT], B2[RT];
    float  rthr[RT];
    float  runmin[RT];
    int    runct[RT];
    const __bf16 kone = (__bf16)1.0f;
    const __bf16 kzb  = (__bf16)0.0f;
    const f32x16 kz = {0.0f,0.0f,0.0f,0.0f,0.0f,0.0f,0.0f,0.0f,
                       0.0f,0.0f,0.0f,0.0f,0.0f,0.0f,0.0f,0.0f};

    // Hoisted LDS read bases for pass 1 (hh-uniform pointers).
    const size_t lnoff = (size_t)ln * 8;
    const char* bCh = (const char*)ldsH + 0 * (NP * 8) + lnoff;
    const char* bCm = (const char*)ldsH + 1 * (NP * 8) + lnoff;
    const char* bCl = (const char*)ldsH + 2 * (NP * 8) + lnoff;
    const char* bCs = (const char*)ldsH + 3 * (NP * 8) + lnoff;
    const char* bLo2 = hh ? bCm : bCl;   // a2 low  half source
    const char* bHi2 = hh ? bCs : bCh;   // a2 high half source

// ---- Stage one column record (raw vis features R0..R3) into the half-planes.
#define STAGE_ONE(Mi, R0, R1, R2, R3)                                         \
    {                                                                         \
        float t0 = fmaf((R0), s5, m5);                                        \
        float t1 = fmaf((R1), s6, m6);                                        \
        float t2 = fmaf((R2), s7, m7);                                        \
        float t3 = fmaf((R3), s8, m8);                                        \
        float cs = 0.25f * (t0*t0 + t1*t1 + t2*t2 + t3*t3);                   \
        __bf16 ch0,cm0,cl0,ch1,cm1,cl1,ch2,cm2,cl2,ch3,cm3,cl3,qh,qm,ql;      \
        split3(t0,ch0,cm0,cl0); split3(t1,ch1,cm1,cl1);                       \
        split3(t2,ch2,cm2,cl2); split3(t3,ch3,cm3,cl3); split3(cs,qh,qm,ql);  \
        const __bf16 z=(__bf16)0.0f;                                          \
        uint2* ph=(uint2*)ldsH;                                               \
        ph[0*NP+(Mi)]=make_uint2(pk2(ch0,ch1),pk2(ch2,ch3));                  \
        ph[1*NP+(Mi)]=make_uint2(pk2(cm0,cm1),pk2(cm2,cm3));                  \
        ph[2*NP+(Mi)]=make_uint2(pk2(cl0,cl1),pk2(cl2,cl3));                  \
        ph[3*NP+(Mi)]=make_uint2(pk2(qh,qm),pk2(ql,z));                       \
    }

// ---- Build B fragments + threshold for one row tile from raw R0..R3.
#define BPREP_ONE(RTi, R0, R1, R2, R3)                                        \
    {                                                                         \
        float t0 = fmaf((R0), s5, m5);                                        \
        float t1 = fmaf((R1), s6, m6);                                        \
        float t2 = fmaf((R2), s7, m7);                                        \
        float t3 = fmaf((R3), s8, m8);                                        \
        float rss = 0.25f * (t0*t0 + t1*t1 + t2*t2 + t3*t3);                  \
        rthr[RTi] = 6.0f - rss;                                               \
        float r0 = -0.5f*t0, r1 = -0.5f*t1, r2 = -0.5f*t2, r3 = -0.5f*t3;     \
        __bf16 rh0,rm0,rl0,rh1,rm1,rl1,rh2,rm2,rl2,rh3,rm3,rl3;               \
        split3(r0,rh0,rm0,rl0); split3(r1,rh1,rm1,rl1);                       \
        split3(r2,rh2,rm2,rl2); split3(r3,rh3,rm3,rl3);                       \
        __bf16 p0 = hh ? rm0 : rh0;                                           \
        __bf16 p1 = hh ? rm1 : rh1;                                           \
        __bf16 p2 = hh ? rm2 : rh2;                                           \
        __bf16 p3 = hh ? rm3 : rh3;                                           \
        bf16x8 b1;                                                            \
        b1[0]=p0; b1[1]=p1; b1[2]=p2; b1[3]=p3;                               \
        b1[4]=p0; b1[5]=p1; b1[6]=p2; b1[7]=p3;                               \
        __bf16 q0 = hh ? rl0 : rh0;                                           \
        __bf16 q1 = hh ? rl1 : rh1;                                           \
        __bf16 q2 = hh ? rl2 : rh2;                                           \
        __bf16 q3 = hh ? rl3 : rh3;                                           \
        bf16x8 b2;                                                            \
        b2[0]=q0; b2[1]=q1; b2[2]=q2; b2[3]=q3;                               \
        b2[4]= hh ? kone : rl0;                                               \
        b2[5]= hh ? kone : rl1;                                               \
        b2[6]= hh ? kone : rl2;                                               \
        b2[7]= hh ? kzb  : rl3;                                               \
        B1[RTi]=b1; B2[RTi]=b2;                                               \
    }

#define TRACK(RT_, A_, CT_)                                                   \
    {                                                                         \
        float u0 = min3f(A_[0],  A_[1],  A_[2]);                              \
        float u1 = min3f(A_[3],  A_[4],  A_[5]);                              \
        float u2 = min3f(A_[6],  A_[7],  A_[8]);                              \
        float u3 = min3f(A_[9],  A_[10], A_[11]);                             \
        float u4 = min3f(A_[12], A_[13], A_[14]);                             \
        float mn = fminf(min3f(u0, u1, u2), min3f(u3, u4, A_[15]));           \
        bool lt = mn < runmin[RT_];          /* strict < keeps FIRST ct */    \
        runmin[RT_] = fminf(runmin[RT_], mn);                                 \
        runct[RT_]  = lt ? (CT_) : runct[RT_];                                \
    }

// ---- Pass 1 (R10 verbatim): 32 col-tiles, 4 ds_read_b64, 4+4 MFMAs, track.
#define PASS1                                                                 \
    _Pragma("unroll")                                                         \
    for (int rt = 0; rt < RT; ++rt) { runmin[rt] = 3.0e38f; runct[rt] = 0; }  \
    for (int ct = 0; ct < 32; ++ct) {                                         \
        const size_t off = (size_t)ct * 256;                                  \
        bf16x8 a1, a2;                                                        \
        *((uint2*)&a1)     = *(const uint2*)(bCh + off);                      \
        *((uint2*)&a1 + 1) = *(const uint2*)(bCm + off);                      \
        *((uint2*)&a2)     = *(const uint2*)(bLo2 + off);                     \
        *((uint2*)&a2 + 1) = *(const uint2*)(bHi2 + off);                     \
        f32x16 ac0 = __builtin_amdgcn_mfma_f32_32x32x16_bf16(a1, B1[0], kz, 0, 0, 0); \
        f32x16 ac1 = __builtin_amdgcn_mfma_f32_32x32x16_bf16(a1, B1[1], kz, 0, 0, 0); \
        f32x16 ac2 = __builtin_amdgcn_mfma_f32_32x32x16_bf16(a1, B1[2], kz, 0, 0, 0); \
        f32x16 ac3 = __builtin_amdgcn_mfma_f32_32x32x16_bf16(a1, B1[3], kz, 0, 0, 0); \
        ac0 = __builtin_amdgcn_mfma_f32_32x32x16_bf16(a2, B2[0], ac0, 0, 0, 0); \
        ac1 = __builtin_amdgcn_mfma_f32_32x32x16_bf16(a2, B2[1], ac1, 0, 0, 0); \
        ac2 = __builtin_amdgcn_mfma_f32_32x32x16_bf16(a2, B2[2], ac2, 0, 0, 0); \
        ac3 = __builtin_amdgcn_mfma_f32_32x32x16_bf16(a2, B2[3], ac3, 0, 0, 0); \
        TRACK(0, ac0, ct)                                                     \
        TRACK(1, ac1, ct)                                                     \
        TRACK(2, ac2, ct)                                                     \
        TRACK(3, ac3, ct)                                                     \
    }

// ---- Merge k-halves and publish (ct, thr) per row to dedicated scratch.
#define MERGE_PUBLISH                                                         \
    _Pragma("unroll")                                                         \
    for (int rt = 0; rt < RT; ++rt) {                                         \
        float bv = runmin[rt];                                                \
        int   bc = runct[rt];                                                 \
        float ov = __shfl_xor(bv, 32);                                        \
        int   oc = __shfl_xor(bc, 32);                                        \
        bool take = (ov < bv) || (ov == bv && oc < bc);                       \
        bv = take ? ov : bv;                                                  \
        bc = take ? oc : bc;                                                  \
        if (hh == 0) {                                                        \
            int n = wv * 128 + rt * 32 + ln;                                  \
            sCtA[n]  = bc;                                                    \
            sThrA[n] = rthr[rt];                                              \
        }                                                                     \
    }

// ---- Epilogue (R4/R10 verbatim): 32-col fp32 rescan from GLOBAL.
#define EPILOGUE(ROWSRC, COLSRC)                                              \
    for (int q = 0; q < 2; ++q) {                                             \
        int n = tid * 2 + q;                                                  \
        int ct = sCtA[n];                                                     \
        float thr = sThrA[n];                                                 \
        const float* pr = (ROWSRC) + (size_t)n * FD;                          \
        float t0 = fmaf(pr[5], s5, m5);                                       \
        float t1 = fmaf(pr[6], s6, m6);                                       \
        float t2 = fmaf(pr[7], s7, m7);                                       \
        float t3 = fmaf(pr[8], s8, m8);                                       \
        float vx = -0.5f*t0, vy = -0.5f*t1, vz = -0.5f*t2, vw = -0.5f*t3;     \
        float best = 3.0e38f;                                                 \
        int bidx = 0;                                                         \
        const int mbase = ct * 32;                                            \
        _Pragma("unroll 4")                                                   \
        for (int j = 0; j < 32; ++j) {                                        \
            const float* pc = (COLSRC) + (size_t)(mbase + j) * FD;            \
            float c0 = fmaf(pc[5], s5, m5);                                   \
            float c1 = fmaf(pc[6], s6, m6);                                   \
            float c2 = fmaf(pc[7], s7, m7);                                   \
            float c3 = fmaf(pc[8], s8, m8);                                   \
            float cs = 0.25f * (c0*c0 + c1*c1 + c2*c2 + c3*c3);               \
            float dd = fmaf(vx, c0, cs);                                      \
            dd = fmaf(vy, c1, dd);                                            \
            dd = fmaf(vz, c2, dd);                                            \
            dd = fmaf(vw, c3, dd);                                            \
            if (dd < best) { best = dd; bidx = mbase + j; }                   \
        }                                                                     \
        const float* pw = (COLSRC) + (size_t)bidx * FD;                       \
        float gx = fmaf(pw[0], std0, mean0);                                  \
        float gy = fmaf(pw[1], std1, mean1);                                  \
        float ax = fmaf(pr[0], std0, mean0);                                  \
        float ay = fmaf(pr[1], std1, mean1);                                  \
        float dx = ax - gx;                                                   \
        float dy = ay - gy;                                                   \
        float dist = sqrtf(dx*dx + dy*dy);                                    \
        if (best > thr) dist = 1.0f;                                          \
        sum += dist;                                                          \
    }

    // ================= UNIT 0: rows = srcA (ag), cols = srcD (dg) ==========
    for (int m = tid; m < NP; m += TPB)
        STAGE_ONE(m, srcD[(size_t)m*FD+5], srcD[(size_t)m*FD+6],
                     srcD[(size_t)m*FD+7], srcD[(size_t)m*FD+8])
#pragma unroll
    for (int rt = 0; rt < RT; ++rt) {
        const float* p = srcA + (size_t)(wv*128 + rt*32 + ln) * FD;
        BPREP_ONE(rt, p[5], p[6], p[7], p[8])
    }
    __syncthreads();

    // ---- Prefetch u1 raw inputs NOW (in flight through pass1(u0)) [T14].
    float cA[4], cB[4], rP[RT][4];
    {
        const float* p0 = srcA + (size_t)tid * FD;
        const float* p1 = srcA + (size_t)(tid + 512) * FD;
#pragma unroll
        for (int j = 0; j < 4; ++j) { cA[j] = p0[5+j]; cB[j] = p1[5+j]; }
#pragma unroll
        for (int rt = 0; rt < RT; ++rt) {
            const float* pr = srcD + (size_t)(wv*128 + rt*32 + ln) * FD;
#pragma unroll
            for (int j = 0; j < 4; ++j) rP[rt][j] = pr[5+j];
        }
    }

    PASS1
    MERGE_PUBLISH
    __syncthreads();   // pass1(u0) LDS reads done; publishes visible

    // ---- Restage planes + B fragments for u1 from prefetched regs, then
    //      epilogue(u0) (reads only global + sCtA/sThrA scratch).
    STAGE_ONE(tid,       cA[0], cA[1], cA[2], cA[3])
    STAGE_ONE(tid + 512, cB[0], cB[1], cB[2], cB[3])
#pragma unroll
    for (int rt = 0; rt < RT; ++rt)
        BPREP_ONE(rt, rP[rt][0], rP[rt][1], rP[rt][2], rP[rt][3])

    float sum = 0.0f;
    EPILOGUE(srcA, srcD)
    __syncthreads();   // u1 planes ready; u0 scratch reads done

    // ================= UNIT 1: rows = srcD (dg), cols = srcA (ag) ==========
    PASS1
    MERGE_PUBLISH
    __syncthreads();

    EPILOGUE(srcD, srcA)

    // ---- Reduce both units: wave shuffle, cross-wave LDS, ONE atomic.
    for (int o = 32; o > 0; o >>= 1) sum += __shfl_down(sum, o, 64);
    if ((tid & 63) == 0) red[tid >> 6] = sum;
    __syncthreads();
    if (tid == 0) {
        float s = red[0] + red[1] + red[2] + red[3]
                + red[4] + red[5] + red[6] + red[7];
        // out[b] accumulates over 4 view-blocks x (2 dirs in-block) / 8192
        atomicAdd(&out[bx >> 2], s * (-1.0f / 8192.0f));
    }
#undef STAGE_ONE
#undef BPREP_ONE
#undef TRACK
#undef PASS1
#undef MERGE_PUBLISH
#undef EPILOGUE
}

extern "C" void kernel_launch(void* const* d_in, const int* in_sizes, int n_in,
                              void* d_out, int out_size, void* d_ws, size_t ws_size,
                              hipStream_t stream)
{
    const float* ag = (const float*)d_in[0];   // achieved_goal (128,4,1024,10)
    const float* dg = (const float*)d_in[1];   // desired_goal  (128,4,1024,10)
    const float* nm = (const float*)d_in[2];   // norm_mean (10,)
    const float* ns = (const float*)d_in[3];   // norm_std  (10,)

    hipMemsetAsync(d_out, 0, BSZ * sizeof(float), stream);   // out is accumulated
    chamfer_pairs<<<BSZ * 4, TPB, 0, stream>>>(ag, dg, nm, ns, (float*)d_out);
}

// Round 12
// 204.137 us; speedup vs baseline: 1.0895x; 1.0895x over previous
//
#include <hip/hip_runtime.h>
#include <cstdint>
#include <cstddef>

#define NP  1024
#define FD  10
#define BSZ 128
#define TPB 512   // 8 waves; each wave owns 128 rows (4 row-tiles of 32)
#define NW  8
#define RT  4     // row-tiles per wave

// R12 = R11 (persistent 2-unit blocks) with the u1 register-prefetch REMOVED.
// R11's prefetch regs had to live across PASS1 (peak pressure) -> 75MB of
// spill traffic (the R7 failure mode again). Unit-1 staging now re-reads its
// inputs from global AFTER the u0 barrier (L2-hot: u0 just read those lines),
// hidden under epilogue(u0). Register pressure = R10's proven-clean set.
// grid 512 (2 blocks/CU, one flat round); block bx runs d=0 (rows=ag,
// cols=dg) then d=1 (rows=dg, cols=ag); halves launches, staging ramps,
// atomics. Numerics IDENTICAL to R10/R11 (absmax 0.0 x10):
// d = cs - 2 r.c via bf16 split-3 in K=32, two chained 32x32x16 MFMAs
// (4 concurrent rt-chains); tile-level (min, ct) tracking, strict <
// first-ct; shfl_xor(32) lexicographic merge; 32-col fp32 global-rescan
// epilogue (bit-identical staging-chain recompute, ascending j + strict <
// = reference first-index argmin).
typedef __attribute__((ext_vector_type(8)))  __bf16 bf16x8;
typedef __attribute__((ext_vector_type(16))) float  f32x16;

__device__ inline unsigned int pk2(__bf16 a, __bf16 b) {
    union { __bf16 h; unsigned short u; } ua, ub;
    ua.h = a; ub.h = b;
    return (unsigned int)ua.u | ((unsigned int)ub.u << 16);
}

__device__ inline void split3(float x, __bf16& h, __bf16& m, __bf16& l) {
    h = (__bf16)x;
    float r1 = x - (float)h;    // exact (h carries x's exponent, 8-bit mantissa)
    m = (__bf16)r1;
    float r2 = r1 - (float)m;   // exact
    l = (__bf16)r2;
}

__device__ inline float min3f(float a, float b, float c) {
    return fminf(fminf(a, b), c);   // fuses to v_min3_f32; order-invariant exact
}

extern "C" __global__ __launch_bounds__(TPB, 4)   // VGPR cap 128
void chamfer_pairs(const float* __restrict__ ag, const float* __restrict__ dg,
                   const float* __restrict__ nmean, const float* __restrict__ nstd,
                   float* __restrict__ out /* [BSZ], pre-zeroed */)
{
    // Four 8-byte half-planes {Ch, Cm, Cl, cs3} = 32 KB, + dedicated scratch
    // for per-row (ct, thr) so u1's restage can't clobber u0's epilogue.
    __shared__ __align__(16) unsigned int ldsH[4 * NP * 2];
    __shared__ int   sCtA[NP];
    __shared__ float sThrA[NP];
    __shared__ float red[NW];

    const int bx   = blockIdx.x;        // 0..511; pair = bx
    const int tid  = threadIdx.x;
    const int wv   = tid >> 6;          // wave 0..7
    const int l    = tid & 63;
    const int ln   = l & 31;            // lane's row slot / col slot
    const int hh   = l >> 5;            // k-half owner

    const float* srcA = ag + (size_t)bx * (NP * FD);   // achieved (u0 rows, u1 cols)
    const float* srcD = dg + (size_t)bx * (NP * FD);   // desired  (u0 cols, u1 rows)

    // -2*(std, mean) for vis features 5..8 (uniform -> scalar regs).
    const float s5 = -2.0f * nstd[5], m5 = -2.0f * nmean[5];
    const float s6 = -2.0f * nstd[6], m6 = -2.0f * nmean[6];
    const float s7 = -2.0f * nstd[7], m7 = -2.0f * nmean[7];
    const float s8 = -2.0f * nstd[8], m8 = -2.0f * nmean[8];
    const float std0 = nstd[0], mean0 = nmean[0];
    const float std1 = nstd[1], mean1 = nmean[1];

    bf16x8 B1[RT], B2[RT];
    float  rthr[RT];
    float  runmin[RT];
    int    runct[RT];
    const __bf16 kone = (__bf16)1.0f;
    const __bf16 kzb  = (__bf16)0.0f;
    const f32x16 kz = {0.0f,0.0f,0.0f,0.0f,0.0f,0.0f,0.0f,0.0f,
                       0.0f,0.0f,0.0f,0.0f,0.0f,0.0f,0.0f,0.0f};

    // Hoisted LDS read bases for pass 1 (hh-uniform pointers).
    const size_t lnoff = (size_t)ln * 8;
    const char* bCh = (const char*)ldsH + 0 * (NP * 8) + lnoff;
    const char* bCm = (const char*)ldsH + 1 * (NP * 8) + lnoff;
    const char* bCl = (const char*)ldsH + 2 * (NP * 8) + lnoff;
    const char* bCs = (const char*)ldsH + 3 * (NP * 8) + lnoff;
    const char* bLo2 = hh ? bCm : bCl;   // a2 low  half source
    const char* bHi2 = hh ? bCs : bCh;   // a2 high half source

// ---- Stage one column record (raw vis features R0..R3) into the half-planes.
#define STAGE_ONE(Mi, R0, R1, R2, R3)                                         \
    {                                                                         \
        float t0 = fmaf((R0), s5, m5);                                        \
        float t1 = fmaf((R1), s6, m6);                                        \
        float t2 = fmaf((R2), s7, m7);                                        \
        float t3 = fmaf((R3), s8, m8);                                        \
        float cs = 0.25f * (t0*t0 + t1*t1 + t2*t2 + t3*t3);                   \
        __bf16 ch0,cm0,cl0,ch1,cm1,cl1,ch2,cm2,cl2,ch3,cm3,cl3,qh,qm,ql;      \
        split3(t0,ch0,cm0,cl0); split3(t1,ch1,cm1,cl1);                       \
        split3(t2,ch2,cm2,cl2); split3(t3,ch3,cm3,cl3); split3(cs,qh,qm,ql);  \
        const __bf16 z=(__bf16)0.0f;                                          \
        uint2* ph=(uint2*)ldsH;                                               \
        ph[0*NP+(Mi)]=make_uint2(pk2(ch0,ch1),pk2(ch2,ch3));                  \
        ph[1*NP+(Mi)]=make_uint2(pk2(cm0,cm1),pk2(cm2,cm3));                  \
        ph[2*NP+(Mi)]=make_uint2(pk2(cl0,cl1),pk2(cl2,cl3));                  \
        ph[3*NP+(Mi)]=make_uint2(pk2(qh,qm),pk2(ql,z));                       \
    }

// ---- Build B fragments + threshold for one row tile from raw R0..R3.
#define BPREP_ONE(RTi, R0, R1, R2, R3)                                        \
    {                                                                         \
        float t0 = fmaf((R0), s5, m5);                                        \
        float t1 = fmaf((R1), s6, m6);                                        \
        float t2 = fmaf((R2), s7, m7);                                        \
        float t3 = fmaf((R3), s8, m8);                                        \
        float rss = 0.25f * (t0*t0 + t1*t1 + t2*t2 + t3*t3);                  \
        rthr[RTi] = 6.0f - rss;                                               \
        float r0 = -0.5f*t0, r1 = -0.5f*t1, r2 = -0.5f*t2, r3 = -0.5f*t3;     \
        __bf16 rh0,rm0,rl0,rh1,rm1,rl1,rh2,rm2,rl2,rh3,rm3,rl3;               \
        split3(r0,rh0,rm0,rl0); split3(r1,rh1,rm1,rl1);                       \
        split3(r2,rh2,rm2,rl2); split3(r3,rh3,rm3,rl3);                       \
        __bf16 p0 = hh ? rm0 : rh0;                                           \
        __bf16 p1 = hh ? rm1 : rh1;                                           \
        __bf16 p2 = hh ? rm2 : rh2;                                           \
        __bf16 p3 = hh ? rm3 : rh3;                                           \
        bf16x8 b1;                                                            \
        b1[0]=p0; b1[1]=p1; b1[2]=p2; b1[3]=p3;                               \
        b1[4]=p0; b1[5]=p1; b1[6]=p2; b1[7]=p3;                               \
        __bf16 q0 = hh ? rl0 : rh0;                                           \
        __bf16 q1 = hh ? rl1 : rh1;                                           \
        __bf16 q2 = hh ? rl2 : rh2;                                           \
        __bf16 q3 = hh ? rl3 : rh3;                                           \
        bf16x8 b2;                                                            \
        b2[0]=q0; b2[1]=q1; b2[2]=q2; b2[3]=q3;                               \
        b2[4]= hh ? kone : rl0;                                               \
        b2[5]= hh ? kone : rl1;                                               \
        b2[6]= hh ? kone : rl2;                                               \
        b2[7]= hh ? kzb  : rl3;                                               \
        B1[RTi]=b1; B2[RTi]=b2;                                               \
    }

#define TRACK(RT_, A_, CT_)                                                   \
    {                                                                         \
        float u0 = min3f(A_[0],  A_[1],  A_[2]);                              \
        float u1 = min3f(A_[3],  A_[4],  A_[5]);                              \
        float u2 = min3f(A_[6],  A_[7],  A_[8]);                              \
        float u3 = min3f(A_[9],  A_[10], A_[11]);                             \
        float u4 = min3f(A_[12], A_[13], A_[14]);                             \
        float mn = fminf(min3f(u0, u1, u2), min3f(u3, u4, A_[15]));           \
        bool lt = mn < runmin[RT_];          /* strict < keeps FIRST ct */    \
        runmin[RT_] = fminf(runmin[RT_], mn);                                 \
        runct[RT_]  = lt ? (CT_) : runct[RT_];                                \
    }

// ---- Pass 1 (R10 verbatim): 32 col-tiles, 4 ds_read_b64, 4+4 MFMAs, track.
#define PASS1                                                                 \
    _Pragma("unroll")                                                         \
    for (int rt = 0; rt < RT; ++rt) { runmin[rt] = 3.0e38f; runct[rt] = 0; }  \
    for (int ct = 0; ct < 32; ++ct) {                                         \
        const size_t off = (size_t)ct * 256;                                  \
        bf16x8 a1, a2;                                                        \
        *((uint2*)&a1)     = *(const uint2*)(bCh + off);                      \
        *((uint2*)&a1 + 1) = *(const uint2*)(bCm + off);                      \
        *((uint2*)&a2)     = *(const uint2*)(bLo2 + off);                     \
        *((uint2*)&a2 + 1) = *(const uint2*)(bHi2 + off);                     \
        f32x16 ac0 = __builtin_amdgcn_mfma_f32_32x32x16_bf16(a1, B1[0], kz, 0, 0, 0); \
        f32x16 ac1 = __builtin_amdgcn_mfma_f32_32x32x16_bf16(a1, B1[1], kz, 0, 0, 0); \
        f32x16 ac2 = __builtin_amdgcn_mfma_f32_32x32x16_bf16(a1, B1[2], kz, 0, 0, 0); \
        f32x16 ac3 = __builtin_amdgcn_mfma_f32_32x32x16_bf16(a1, B1[3], kz, 0, 0, 0); \
        ac0 = __builtin_amdgcn_mfma_f32_32x32x16_bf16(a2, B2[0], ac0, 0, 0, 0); \
        ac1 = __builtin_amdgcn_mfma_f32_32x32x16_bf16(a2, B2[1], ac1, 0, 0, 0); \
        ac2 = __builtin_amdgcn_mfma_f32_32x32x16_bf16(a2, B2[2], ac2, 0, 0, 0); \
        ac3 = __builtin_amdgcn_mfma_f32_32x32x16_bf16(a2, B2[3], ac3, 0, 0, 0); \
        TRACK(0, ac0, ct)                                                     \
        TRACK(1, ac1, ct)                                                     \
        TRACK(2, ac2, ct)                                                     \
        TRACK(3, ac3, ct)                                                     \
    }

// ---- Merge k-halves and publish (ct, thr) per row to dedicated scratch.
#define MERGE_PUBLISH                                                         \
    _Pragma("unroll")                                                         \
    for (int rt = 0; rt < RT; ++rt) {                                         \
        float bv = runmin[rt];                                                \
        int   bc = runct[rt];                                                 \
        float ov = __shfl_xor(bv, 32);                                        \
        int   oc = __shfl_xor(bc, 32);                                        \
        bool take = (ov < bv) || (ov == bv && oc < bc);                       \
        bv = take ? ov : bv;                                                  \
        bc = take ? oc : bc;                                                  \
        if (hh == 0) {                                                        \
            int n = wv * 128 + rt * 32 + ln;                                  \
            sCtA[n]  = bc;                                                    \
            sThrA[n] = rthr[rt];                                              \
        }                                                                     \
    }

// ---- Epilogue (R4/R10 verbatim): 32-col fp32 rescan from GLOBAL.
#define EPILOGUE(ROWSRC, COLSRC)                                              \
    for (int q = 0; q < 2; ++q) {                                             \
        int n = tid * 2 + q;                                                  \
        int ct = sCtA[n];                                                     \
        float thr = sThrA[n];                                                 \
        const float* pr = (ROWSRC) + (size_t)n * FD;                          \
        float t0 = fmaf(pr[5], s5, m5);                                       \
        float t1 = fmaf(pr[6], s6, m6);                                       \
        float t2 = fmaf(pr[7], s7, m7);                                       \
        float t3 = fmaf(pr[8], s8, m8);                                       \
        float vx = -0.5f*t0, vy = -0.5f*t1, vz = -0.5f*t2, vw = -0.5f*t3;     \
        float best = 3.0e38f;                                                 \
        int bidx = 0;                                                         \
        const int mbase = ct * 32;                                            \
        _Pragma("unroll 4")                                                   \
        for (int j = 0; j < 32; ++j) {                                        \
            const float* pc = (COLSRC) + (size_t)(mbase + j) * FD;            \
            float c0 = fmaf(pc[5], s5, m5);                                   \
            float c1 = fmaf(pc[6], s6, m6);                                   \
            float c2 = fmaf(pc[7], s7, m7);                                   \
            float c3 = fmaf(pc[8], s8, m8);                                   \
            float cs = 0.25f * (c0*c0 + c1*c1 + c2*c2 + c3*c3);               \
            float dd = fmaf(vx, c0, cs);                                      \
            dd = fmaf(vy, c1, dd);                                            \
            dd = fmaf(vz, c2, dd);                                            \
            dd = fmaf(vw, c3, dd);                                            \
            if (dd < best) { best = dd; bidx = mbase + j; }                   \
        }                                                                     \
        const float* pw = (COLSRC) + (size_t)bidx * FD;                       \
        float gx = fmaf(pw[0], std0, mean0);                                  \
        float gy = fmaf(pw[1], std1, mean1);                                  \
        float ax = fmaf(pr[0], std0, mean0);                                  \
        float ay = fmaf(pr[1], std1, mean1);                                  \
        float dx = ax - gx;                                                   \
        float dy = ay - gy;                                                   \
        float dist = sqrtf(dx*dx + dy*dy);                                    \
        if (best > thr) dist = 1.0f;                                          \
        sum += dist;                                                          \
    }

    // ================= UNIT 0: rows = srcA (ag), cols = srcD (dg) ==========
    for (int m = tid; m < NP; m += TPB)
        STAGE_ONE(m, srcD[(size_t)m*FD+5], srcD[(size_t)m*FD+6],
                     srcD[(size_t)m*FD+7], srcD[(size_t)m*FD+8])
#pragma unroll
    for (int rt = 0; rt < RT; ++rt) {
        const float* p = srcA + (size_t)(wv*128 + rt*32 + ln) * FD;
        BPREP_ONE(rt, p[5], p[6], p[7], p[8])
    }
    __syncthreads();

    PASS1
    MERGE_PUBLISH
    __syncthreads();   // pass1(u0) LDS reads done; publishes visible

    // ---- Restage planes + B fragments for u1 from GLOBAL (L2-hot: u0 just
    //      read these lines; no registers live across PASS1 -> no spills).
    //      LDS-write latency hides under epilogue(u0)'s global gathers.
    for (int m = tid; m < NP; m += TPB)
        STAGE_ONE(m, srcA[(size_t)m*FD+5], srcA[(size_t)m*FD+6],
                     srcA[(size_t)m*FD+7], srcA[(size_t)m*FD+8])
#pragma unroll
    for (int rt = 0; rt < RT; ++rt) {
        const float* p = srcD + (size_t)(wv*128 + rt*32 + ln) * FD;
        BPREP_ONE(rt, p[5], p[6], p[7], p[8])
    }

    float sum = 0.0f;
    EPILOGUE(srcA, srcD)
    __syncthreads();   // u1 planes ready; u0 scratch reads done

    // ================= UNIT 1: rows = srcD (dg), cols = srcA (ag) ==========
    PASS1
    MERGE_PUBLISH
    __syncthreads();

    EPILOGUE(srcD, srcA)

    // ---- Reduce both units: wave shuffle, cross-wave LDS, ONE atomic.
    for (int o = 32; o > 0; o >>= 1) sum += __shfl_down(sum, o, 64);
    if ((tid & 63) == 0) red[tid >> 6] = sum;
    __syncthreads();
    if (tid == 0) {
        float s = red[0] + red[1] + red[2] + red[3]
                + red[4] + red[5] + red[6] + red[7];
        // out[b] accumulates over 4 view-blocks x (2 dirs in-block) / 8192
        atomicAdd(&out[bx >> 2], s * (-1.0f / 8192.0f));
    }
#undef STAGE_ONE
#undef BPREP_ONE
#undef TRACK
#undef PASS1
#undef MERGE_PUBLISH
#undef EPILOGUE
}

extern "C" void kernel_launch(void* const* d_in, const int* in_sizes, int n_in,
                              void* d_out, int out_size, void* d_ws, size_t ws_size,
                              hipStream_t stream)
{
    const float* ag = (const float*)d_in[0];   // achieved_goal (128,4,1024,10)
    const float* dg = (const float*)d_in[1];   // desired_goal  (128,4,1024,10)
    const float* nm = (const float*)d_in[2];   // norm_mean (10,)
    const float* ns = (const float*)d_in[3];   // norm_std  (10,)

    hipMemsetAsync(d_out, 0, BSZ * sizeof(float), stream);   // out is accumulated
    chamfer_pairs<<<BSZ * 4, TPB, 0, stream>>>(ag, dg, nm, ns, (float*)d_out);
}

// Round 13
// 193.261 us; speedup vs baseline: 1.1508x; 1.0563x over previous
//
#include <hip/hip_runtime.h>
#include <cstdint>
#include <cstddef>

#define NP  1024
#define FD  10
#define BSZ 128
#define TPB 512   // 8 waves; each wave owns 128 rows (4 row-tiles of 32)
#define NW  8
#define RT  4     // row-tiles per wave

// R13 = clean 2-unit persistent blocks: R12 with u1's restage moved AFTER
// epilogue(u0). Strictly sequential phases -- NO value lives across a
// high-pressure region (the R7/R11/R12 spill mode, 96/75/50 MB, is removed
// by construction: B1/B2 die before each epilogue, are rebuilt after).
// Register pressure is phase-wise identical to R10 (proven VGPR 64, 32 KB
// writes). grid 512 = 2 blocks/CU, one flat round; block bx runs d=0
// (rows=ag, cols=dg) then d=1 (rows=dg, cols=ag); halves launches and
// drain tails, one atomic per 2 dirs.
// Numerics IDENTICAL to R10/R11/R12 (absmax 0.0 x11):
// d = cs - 2 r.c via bf16 split-3 in K=32, two chained 32x32x16 MFMAs
// (4 concurrent rt-chains); tile-level (min, ct) tracking, strict <
// first-ct; shfl_xor(32) lexicographic merge; 32-col fp32 global-rescan
// epilogue (bit-identical staging-chain recompute, ascending j + strict <
// = reference first-index argmin).
typedef __attribute__((ext_vector_type(8)))  __bf16 bf16x8;
typedef __attribute__((ext_vector_type(16))) float  f32x16;

__device__ inline unsigned int pk2(__bf16 a, __bf16 b) {
    union { __bf16 h; unsigned short u; } ua, ub;
    ua.h = a; ub.h = b;
    return (unsigned int)ua.u | ((unsigned int)ub.u << 16);
}

__device__ inline void split3(float x, __bf16& h, __bf16& m, __bf16& l) {
    h = (__bf16)x;
    float r1 = x - (float)h;    // exact (h carries x's exponent, 8-bit mantissa)
    m = (__bf16)r1;
    float r2 = r1 - (float)m;   // exact
    l = (__bf16)r2;
}

__device__ inline float min3f(float a, float b, float c) {
    return fminf(fminf(a, b), c);   // fuses to v_min3_f32; order-invariant exact
}

extern "C" __global__ __launch_bounds__(TPB, 4)   // VGPR cap 128
void chamfer_pairs(const float* __restrict__ ag, const float* __restrict__ dg,
                   const float* __restrict__ nmean, const float* __restrict__ nstd,
                   float* __restrict__ out /* [BSZ], pre-zeroed */)
{
    // Four 8-byte half-planes {Ch, Cm, Cl, cs3} = 32 KB, + dedicated scratch
    // for per-row (ct, thr) so u1's restage never touches u0's epilogue data.
    __shared__ __align__(16) unsigned int ldsH[4 * NP * 2];
    __shared__ int   sCtA[NP];
    __shared__ float sThrA[NP];
    __shared__ float red[NW];

    const int bx   = blockIdx.x;        // 0..511; pair = bx
    const int tid  = threadIdx.x;
    const int wv   = tid >> 6;          // wave 0..7
    const int l    = tid & 63;
    const int ln   = l & 31;            // lane's row slot / col slot
    const int hh   = l >> 5;            // k-half owner

    const float* srcA = ag + (size_t)bx * (NP * FD);   // achieved (u0 rows, u1 cols)
    const float* srcD = dg + (size_t)bx * (NP * FD);   // desired  (u0 cols, u1 rows)

    // -2*(std, mean) for vis features 5..8 (uniform -> scalar regs).
    const float s5 = -2.0f * nstd[5], m5 = -2.0f * nmean[5];
    const float s6 = -2.0f * nstd[6], m6 = -2.0f * nmean[6];
    const float s7 = -2.0f * nstd[7], m7 = -2.0f * nmean[7];
    const float s8 = -2.0f * nstd[8], m8 = -2.0f * nmean[8];
    const float std0 = nstd[0], mean0 = nmean[0];
    const float std1 = nstd[1], mean1 = nmean[1];

    bf16x8 B1[RT], B2[RT];
    float  rthr[RT];
    float  runmin[RT];
    int    runct[RT];
    const __bf16 kone = (__bf16)1.0f;
    const __bf16 kzb  = (__bf16)0.0f;
    const f32x16 kz = {0.0f,0.0f,0.0f,0.0f,0.0f,0.0f,0.0f,0.0f,
                       0.0f,0.0f,0.0f,0.0f,0.0f,0.0f,0.0f,0.0f};

    // Hoisted LDS read bases for pass 1 (hh-uniform pointers).
    const size_t lnoff = (size_t)ln * 8;
    const char* bCh = (const char*)ldsH + 0 * (NP * 8) + lnoff;
    const char* bCm = (const char*)ldsH + 1 * (NP * 8) + lnoff;
    const char* bCl = (const char*)ldsH + 2 * (NP * 8) + lnoff;
    const char* bCs = (const char*)ldsH + 3 * (NP * 8) + lnoff;
    const char* bLo2 = hh ? bCm : bCl;   // a2 low  half source
    const char* bHi2 = hh ? bCs : bCh;   // a2 high half source

// ---- Stage one column record (raw vis features R0..R3) into the half-planes.
#define STAGE_ONE(Mi, R0, R1, R2, R3)                                         \
    {                                                                         \
        float t0 = fmaf((R0), s5, m5);                                        \
        float t1 = fmaf((R1), s6, m6);                                        \
        float t2 = fmaf((R2), s7, m7);                                        \
        float t3 = fmaf((R3), s8, m8);                                        \
        float cs = 0.25f * (t0*t0 + t1*t1 + t2*t2 + t3*t3);                   \
        __bf16 ch0,cm0,cl0,ch1,cm1,cl1,ch2,cm2,cl2,ch3,cm3,cl3,qh,qm,ql;      \
        split3(t0,ch0,cm0,cl0); split3(t1,ch1,cm1,cl1);                       \
        split3(t2,ch2,cm2,cl2); split3(t3,ch3,cm3,cl3); split3(cs,qh,qm,ql);  \
        const __bf16 z=(__bf16)0.0f;                                          \
        uint2* ph=(uint2*)ldsH;                                               \
        ph[0*NP+(Mi)]=make_uint2(pk2(ch0,ch1),pk2(ch2,ch3));                  \
        ph[1*NP+(Mi)]=make_uint2(pk2(cm0,cm1),pk2(cm2,cm3));                  \
        ph[2*NP+(Mi)]=make_uint2(pk2(cl0,cl1),pk2(cl2,cl3));                  \
        ph[3*NP+(Mi)]=make_uint2(pk2(qh,qm),pk2(ql,z));                       \
    }

// ---- Build B fragments + threshold for one row tile from raw R0..R3.
#define BPREP_ONE(RTi, R0, R1, R2, R3)                                        \
    {                                                                         \
        float t0 = fmaf((R0), s5, m5);                                        \
        float t1 = fmaf((R1), s6, m6);                                        \
        float t2 = fmaf((R2), s7, m7);                                        \
        float t3 = fmaf((R3), s8, m8);                                        \
        float rss = 0.25f * (t0*t0 + t1*t1 + t2*t2 + t3*t3);                  \
        rthr[RTi] = 6.0f - rss;                                               \
        float r0 = -0.5f*t0, r1 = -0.5f*t1, r2 = -0.5f*t2, r3 = -0.5f*t3;     \
        __bf16 rh0,rm0,rl0,rh1,rm1,rl1,rh2,rm2,rl2,rh3,rm3,rl3;               \
        split3(r0,rh0,rm0,rl0); split3(r1,rh1,rm1,rl1);                       \
        split3(r2,rh2,rm2,rl2); split3(r3,rh3,rm3,rl3);                       \
        __bf16 p0 = hh ? rm0 : rh0;                                           \
        __bf16 p1 = hh ? rm1 : rh1;                                           \
        __bf16 p2 = hh ? rm2 : rh2;                                           \
        __bf16 p3 = hh ? rm3 : rh3;                                           \
        bf16x8 b1;                                                            \
        b1[0]=p0; b1[1]=p1; b1[2]=p2; b1[3]=p3;                               \
        b1[4]=p0; b1[5]=p1; b1[6]=p2; b1[7]=p3;                               \
        __bf16 q0 = hh ? rl0 : rh0;                                           \
        __bf16 q1 = hh ? rl1 : rh1;                                           \
        __bf16 q2 = hh ? rl2 : rh2;                                           \
        __bf16 q3 = hh ? rl3 : rh3;                                           \
        bf16x8 b2;                                                            \
        b2[0]=q0; b2[1]=q1; b2[2]=q2; b2[3]=q3;                               \
        b2[4]= hh ? kone : rl0;                                               \
        b2[5]= hh ? kone : rl1;                                               \
        b2[6]= hh ? kone : rl2;                                               \
        b2[7]= hh ? kzb  : rl3;                                               \
        B1[RTi]=b1; B2[RTi]=b2;                                               \
    }

#define TRACK(RT_, A_, CT_)                                                   \
    {                                                                         \
        float u0 = min3f(A_[0],  A_[1],  A_[2]);                              \
        float u1 = min3f(A_[3],  A_[4],  A_[5]);                              \
        float u2 = min3f(A_[6],  A_[7],  A_[8]);                              \
        float u3 = min3f(A_[9],  A_[10], A_[11]);                             \
        float u4 = min3f(A_[12], A_[13], A_[14]);                             \
        float mn = fminf(min3f(u0, u1, u2), min3f(u3, u4, A_[15]));           \
        bool lt = mn < runmin[RT_];          /* strict < keeps FIRST ct */    \
        runmin[RT_] = fminf(runmin[RT_], mn);                                 \
        runct[RT_]  = lt ? (CT_) : runct[RT_];                                \
    }

// ---- Pass 1 (R10 verbatim): 32 col-tiles, 4 ds_read_b64, 4+4 MFMAs, track.
#define PASS1                                                                 \
    _Pragma("unroll")                                                         \
    for (int rt = 0; rt < RT; ++rt) { runmin[rt] = 3.0e38f; runct[rt] = 0; }  \
    for (int ct = 0; ct < 32; ++ct) {                                         \
        const size_t off = (size_t)ct * 256;                                  \
        bf16x8 a1, a2;                                                        \
        *((uint2*)&a1)     = *(const uint2*)(bCh + off);                      \
        *((uint2*)&a1 + 1) = *(const uint2*)(bCm + off);                      \
        *((uint2*)&a2)     = *(const uint2*)(bLo2 + off);                     \
        *((uint2*)&a2 + 1) = *(const uint2*)(bHi2 + off);                     \
        f32x16 ac0 = __builtin_amdgcn_mfma_f32_32x32x16_bf16(a1, B1[0], kz, 0, 0, 0); \
        f32x16 ac1 = __builtin_amdgcn_mfma_f32_32x32x16_bf16(a1, B1[1], kz, 0, 0, 0); \
        f32x16 ac2 = __builtin_amdgcn_mfma_f32_32x32x16_bf16(a1, B1[2], kz, 0, 0, 0); \
        f32x16 ac3 = __builtin_amdgcn_mfma_f32_32x32x16_bf16(a1, B1[3], kz, 0, 0, 0); \
        ac0 = __builtin_amdgcn_mfma_f32_32x32x16_bf16(a2, B2[0], ac0, 0, 0, 0); \
        ac1 = __builtin_amdgcn_mfma_f32_32x32x16_bf16(a2, B2[1], ac1, 0, 0, 0); \
        ac2 = __builtin_amdgcn_mfma_f32_32x32x16_bf16(a2, B2[2], ac2, 0, 0, 0); \
        ac3 = __builtin_amdgcn_mfma_f32_32x32x16_bf16(a2, B2[3], ac3, 0, 0, 0); \
        TRACK(0, ac0, ct)                                                     \
        TRACK(1, ac1, ct)                                                     \
        TRACK(2, ac2, ct)                                                     \
        TRACK(3, ac3, ct)                                                     \
    }

// ---- Merge k-halves and publish (ct, thr) per row to dedicated scratch.
#define MERGE_PUBLISH                                                         \
    _Pragma("unroll")                                                         \
    for (int rt = 0; rt < RT; ++rt) {                                         \
        float bv = runmin[rt];                                                \
        int   bc = runct[rt];                                                 \
        float ov = __shfl_xor(bv, 32);                                        \
        int   oc = __shfl_xor(bc, 32);                                        \
        bool take = (ov < bv) || (ov == bv && oc < bc);                       \
        bv = take ? ov : bv;                                                  \
        bc = take ? oc : bc;                                                  \
        if (hh == 0) {                                                        \
            int n = wv * 128 + rt * 32 + ln;                                  \
            sCtA[n]  = bc;                                                    \
            sThrA[n] = rthr[rt];                                              \
        }                                                                     \
    }

// ---- Epilogue (R4/R10 verbatim): 32-col fp32 rescan from GLOBAL.
#define EPILOGUE(ROWSRC, COLSRC)                                              \
    for (int q = 0; q < 2; ++q) {                                             \
        int n = tid * 2 + q;                                                  \
        int ct = sCtA[n];                                                     \
        float thr = sThrA[n];                                                 \
        const float* pr = (ROWSRC) + (size_t)n * FD;                          \
        float t0 = fmaf(pr[5], s5, m5);                                       \
        float t1 = fmaf(pr[6], s6, m6);                                       \
        float t2 = fmaf(pr[7], s7, m7);                                       \
        float t3 = fmaf(pr[8], s8, m8);                                       \
        float vx = -0.5f*t0, vy = -0.5f*t1, vz = -0.5f*t2, vw = -0.5f*t3;     \
        float best = 3.0e38f;                                                 \
        int bidx = 0;                                                         \
        const int mbase = ct * 32;                                            \
        _Pragma("unroll 4")                                                   \
        for (int j = 0; j < 32; ++j) {                                        \
            const float* pc = (COLSRC) + (size_t)(mbase + j) * FD;            \
            float c0 = fmaf(pc[5], s5, m5);                                   \
            float c1 = fmaf(pc[6], s6, m6);                                   \
            float c2 = fmaf(pc[7], s7, m7);                                   \
            float c3 = fmaf(pc[8], s8, m8);                                   \
            float cs = 0.25f * (c0*c0 + c1*c1 + c2*c2 + c3*c3);               \
            float dd = fmaf(vx, c0, cs);                                      \
            dd = fmaf(vy, c1, dd);                                            \
            dd = fmaf(vz, c2, dd);                                            \
            dd = fmaf(vw, c3, dd);                                            \
            if (dd < best) { best = dd; bidx = mbase + j; }                   \
        }                                                                     \
        const float* pw = (COLSRC) + (size_t)bidx * FD;                       \
        float gx = fmaf(pw[0], std0, mean0);                                  \
        float gy = fmaf(pw[1], std1, mean1);                                  \
        float ax = fmaf(pr[0], std0, mean0);                                  \
        float ay = fmaf(pr[1], std1, mean1);                                  \
        float dx = ax - gx;                                                   \
        float dy = ay - gy;                                                   \
        float dist = sqrtf(dx*dx + dy*dy);                                    \
        if (best > thr) dist = 1.0f;                                          \
        sum += dist;                                                          \
    }

    float sum = 0.0f;

    // ================= UNIT 0: rows = srcA (ag), cols = srcD (dg) ==========
    for (int m = tid; m < NP; m += TPB)
        STAGE_ONE(m, srcD[(size_t)m*FD+5], srcD[(size_t)m*FD+6],
                     srcD[(size_t)m*FD+7], srcD[(size_t)m*FD+8])
#pragma unroll
    for (int rt = 0; rt < RT; ++rt) {
        const float* p = srcA + (size_t)(wv*128 + rt*32 + ln) * FD;
        BPREP_ONE(rt, p[5], p[6], p[7], p[8])
    }
    __syncthreads();

    PASS1
    MERGE_PUBLISH
    __syncthreads();   // ldsH reads drained; publishes visible

    EPILOGUE(srcA, srcD)   // B1/B2 dead here -- no live range across this

    // ================= UNIT 1: rows = srcD (dg), cols = srcA (ag) ==========
    // Restage AFTER epilogue(u0): strictly sequential, no cross-phase state.
    // Sources are L2-hot (u0 read every line of both tensors).
    for (int m = tid; m < NP; m += TPB)
        STAGE_ONE(m, srcA[(size_t)m*FD+5], srcA[(size_t)m*FD+6],
                     srcA[(size_t)m*FD+7], srcA[(size_t)m*FD+8])
#pragma unroll
    for (int rt = 0; rt < RT; ++rt) {
        const float* p = srcD + (size_t)(wv*128 + rt*32 + ln) * FD;
        BPREP_ONE(rt, p[5], p[6], p[7], p[8])
    }
    __syncthreads();   // u1 planes visible; also fences epilogue(u0) sCtA reads

    PASS1
    MERGE_PUBLISH
    __syncthreads();

    EPILOGUE(srcD, srcA)

    // ---- Reduce both units: wave shuffle, cross-wave LDS, ONE atomic.
    for (int o = 32; o > 0; o >>= 1) sum += __shfl_down(sum, o, 64);
    if ((tid & 63) == 0) red[tid >> 6] = sum;
    __syncthreads();
    if (tid == 0) {
        float s = red[0] + red[1] + red[2] + red[3]
                + red[4] + red[5] + red[6] + red[7];
        // out[b] accumulates over 4 view-blocks x (2 dirs in-block) / 8192
        atomicAdd(&out[bx >> 2], s * (-1.0f / 8192.0f));
    }
#undef STAGE_ONE
#undef BPREP_ONE
#undef TRACK
#undef PASS1
#undef MERGE_PUBLISH
#undef EPILOGUE
}

extern "C" void kernel_launch(void* const* d_in, const int* in_sizes, int n_in,
                              void* d_out, int out_size, void* d_ws, size_t ws_size,
                              hipStream_t stream)
{
    const float* ag = (const float*)d_in[0];   // achieved_goal (128,4,1024,10)
    const float* dg = (const float*)d_in[1];   // desired_goal  (128,4,1024,10)
    const float* nm = (const float*)d_in[2];   // norm_mean (10,)
    const float* ns = (const float*)d_in[3];   // norm_std  (10,)

    hipMemsetAsync(d_out, 0, BSZ * sizeof(float), stream);   // out is accumulated
    chamfer_pairs<<<BSZ * 4, TPB, 0, stream>>>(ag, dg, nm, ns, (float*)d_out);
}